// Round 2
// baseline (862.245 us; speedup 1.0000x reference)
//
#include <hip/hip_runtime.h>
#include <stdint.h>

// WaveletKAN: out = sum_s wavedec(x)[s] @ basis_s[:K_s]
// K segments (db4, symmetric, 4 levels from N=4096): cA4=262, cD4=262, cD3=518, cD2=1029, cD1=2051
// Strategy: fuse into ONE GEMM  [4096 x Kpad] @ [Kpad x 4096], Kpad=4416 (segments padded to x64, zeros).
// Precision: bf16x3 split (A=Ah+Al, B=Bh+Bl; acc = AhBh + AhBl + AlBh) -> ~fp32 accuracy at bf16 MFMA rate.
// Workspace: Ah,Al [4096][4416] bf16 + Bh,Bl [4096][4416] bf16 (B stored transposed [n][k]) = 145 MB.

#define KPAD 4416
#define BM 128
#define BN 128
#define BK 32

typedef __bf16 bf16x8 __attribute__((ext_vector_type(8)));
typedef float f32x4 __attribute__((ext_vector_type(4)));

__device__ __forceinline__ void split_bf(float v, unsigned short& h, unsigned short& l) {
  // round-to-nearest-even fp32 -> bf16 hi, then residual -> bf16 lo
  uint32_t u = __builtin_bit_cast(uint32_t, v);
  uint32_t hr = (u + 0x7FFFu + ((u >> 16) & 1u)) >> 16;
  h = (unsigned short)hr;
  float hf = __builtin_bit_cast(float, hr << 16);
  float d = v - hf;
  uint32_t du = __builtin_bit_cast(uint32_t, d);
  uint32_t lr = (du + 0x7FFFu + ((du >> 16) & 1u)) >> 16;
  l = (unsigned short)lr;
}

// ---------------- DWT: 4 levels of db4 'symmetric' per row, writes split coeffs ----------------
__global__ __launch_bounds__(256) void dwt_kernel(const float* __restrict__ x,
                                                  unsigned short* __restrict__ Ah,
                                                  unsigned short* __restrict__ Al) {
  __shared__ float bufA[4096];
  __shared__ float bufB[2052];
  const int tid = threadIdx.x;
  const int row = blockIdx.x;
  const size_t rowbase = (size_t)row * KPAD;

  {
    const float4* src = (const float4*)(x + (size_t)row * 4096);
    float4* dst = (float4*)bufA;
    for (int i = tid; i < 1024; i += 256) dst[i] = src[i];
  }
  __syncthreads();

  // reversed db4 filters (cross-correlation kernels): kern[j] = DEC[7-j]
  const float LOr[8] = {0.23037781330885523f, 0.7148465705525415f, 0.6308807679295904f,
                        -0.02798376941698385f, -0.18703481171888114f, 0.030841381835986965f,
                        0.032883011666982945f, -0.010597401784997278f};
  const float HIr[8] = {-0.010597401784997278f, -0.032883011666982945f, 0.030841381835986965f,
                        0.18703481171888114f, -0.02798376941698385f, -0.6308807679295904f,
                        0.7148465705525415f, -0.23037781330885523f};
  const int dOff[4] = {2304, 1216, 640, 320}; // cD1, cD2, cD3, cD4 segment offsets

  float* cur = bufA;
  float* nxt = bufB;
  int N = 4096;
  for (int l = 0; l < 4; ++l) {
    const int M = (N + 7) >> 1;
    for (int t = tid; t < M; t += 256) {
      float lo = 0.f, hi = 0.f;
      const int base = 1 + 2 * t; // ext index of first tap (ext = symmetric pad by 7 each side)
      #pragma unroll
      for (int j = 0; j < 8; ++j) {
        const int i = base + j;
        const int idx = (i < 7) ? (6 - i) : ((i < N + 7) ? (i - 7) : (2 * N + 6 - i));
        const float v = cur[idx];
        lo = fmaf(v, LOr[j], lo);
        hi = fmaf(v, HIr[j], hi);
      }
      unsigned short hh, hl;
      split_bf(hi, hh, hl);
      Ah[rowbase + dOff[l] + t] = hh;
      Al[rowbase + dOff[l] + t] = hl;
      if (l < 3) {
        nxt[t] = lo;
      } else {
        unsigned short ch, cl;
        split_bf(lo, ch, cl);
        Ah[rowbase + t] = ch;  // cA4 at segment 0
        Al[rowbase + t] = cl;
      }
    }
    __syncthreads();
    float* tmp = cur; cur = nxt; nxt = tmp;
    N = M;
  }

  // zero the pad gaps so the GEMM K-padding contributes 0
  const int gs[5] = {262, 582, 1158, 2245, 4355};
  const int ge[5] = {320, 640, 1216, 2304, 4416};
  #pragma unroll
  for (int g = 0; g < 5; ++g)
    for (int i = gs[g] + tid; i < ge[g]; i += 256) {
      Ah[rowbase + i] = 0;
      Al[rowbase + i] = 0;
    }
}

// ---------------- Basis gather + transpose + bf16 hi/lo split: Bt[n][k] ----------------
__global__ __launch_bounds__(256) void bconv_kernel(const float* __restrict__ b0, const float* __restrict__ b1,
                                                    const float* __restrict__ b2, const float* __restrict__ b3,
                                                    const float* __restrict__ b4,
                                                    unsigned short* __restrict__ Bh,
                                                    unsigned short* __restrict__ Bl) {
  __shared__ float tile[64][65];
  const int tid = threadIdx.x;
  const int k0 = blockIdx.x * 64; // segment boundaries are multiples of 64, so one segment per tile
  const int n0 = blockIdx.y * 64;
  const int s = (k0 >= 2304) ? 4 : (k0 >= 1216) ? 3 : (k0 >= 640) ? 2 : (k0 >= 320) ? 1 : 0;
  const int offs[5] = {0, 320, 640, 1216, 2304};
  const int lens[5] = {262, 262, 518, 1029, 2051};
  const float* srcs[5] = {b0, b1, b2, b3, b4};
  const float* src = srcs[s];
  const int kl0 = k0 - offs[s];
  const int len = lens[s];

  #pragma unroll
  for (int r = 0; r < 4; ++r) {
    const int kr = r * 16 + (tid >> 4);
    const int nc = (tid & 15) * 4;
    const int kl = kl0 + kr;
    float4 v = make_float4(0.f, 0.f, 0.f, 0.f);
    if (kl < len) v = *(const float4*)(src + (size_t)kl * 4096 + n0 + nc);
    tile[kr][nc] = v.x; tile[kr][nc + 1] = v.y; tile[kr][nc + 2] = v.z; tile[kr][nc + 3] = v.w;
  }
  __syncthreads();

  const int nl = tid >> 2;
  const int kg = (tid & 3) * 16;
  uint4 hv[2]; uint4 lv[2];
  unsigned short* hb = (unsigned short*)hv;
  unsigned short* lb = (unsigned short*)lv;
  #pragma unroll
  for (int j = 0; j < 16; ++j) {
    unsigned short h, l;
    split_bf(tile[kg + j][nl], h, l);
    hb[j] = h; lb[j] = l;
  }
  const size_t dst = (size_t)(n0 + nl) * KPAD + (size_t)(k0 + kg);
  ((uint4*)(Bh + dst))[0] = hv[0];
  ((uint4*)(Bh + dst))[1] = hv[1];
  ((uint4*)(Bl + dst))[0] = lv[0];
  ((uint4*)(Bl + dst))[1] = lv[1];
}

// ---------------- GEMM: 128x128 tile, BK=32, 4 waves, bf16x3, global_load_lds staging ----------------
#define GLD16(g, l)                                                                              \
  __builtin_amdgcn_global_load_lds((const __attribute__((address_space(1))) void*)(g),           \
                                   (__attribute__((address_space(3))) void*)(l), 16, 0, 0)

__global__ __launch_bounds__(256) void gemm_kernel(const unsigned short* __restrict__ Ah,
                                                   const unsigned short* __restrict__ Al,
                                                   const unsigned short* __restrict__ Bh,
                                                   const unsigned short* __restrict__ Bl,
                                                   float* __restrict__ C) {
  __shared__ unsigned short sAh[BM * BK], sAl[BM * BK], sBh[BN * BK], sBl[BN * BK];
  const int tid = threadIdx.x;
  const int wave = tid >> 6;
  const int lane = tid & 63;

  // XCD-aware bijective swizzle (1024 blocks % 8 == 0)
  const int bid = blockIdx.x;
  const int wg = (bid & 7) * 128 + (bid >> 3);
  const int tm = wg >> 5, tn = wg & 31;
  const size_t bm0 = (size_t)tm * BM;
  const size_t bn0 = (size_t)tn * BN;
  const int wm = wave >> 1, wn = wave & 1; // 2x2 wave grid, 64x64 per wave

  f32x4 acc[4][4] = {};

  for (int k0 = 0; k0 < KPAD; k0 += BK) {
    #pragma unroll
    for (int r = 0; r < 2; ++r) {
      const int i = r * 256 + tid;
      const int row_ = i >> 2;            // 0..127
      const int kqb = (i & 3) * 16;       // byte offset within the 64-byte k-row
      const size_t aoff = (bm0 + (size_t)row_) * KPAD + (size_t)k0; // elements
      const size_t boff = (bn0 + (size_t)row_) * KPAD + (size_t)k0;
      const int ldso = wave * 1024 + r * 4096; // wave-uniform LDS byte base
      GLD16((const char*)(Ah + aoff) + kqb, (char*)sAh + ldso);
      GLD16((const char*)(Al + aoff) + kqb, (char*)sAl + ldso);
      GLD16((const char*)(Bh + boff) + kqb, (char*)sBh + ldso);
      GLD16((const char*)(Bl + boff) + kqb, (char*)sBl + ldso);
    }
    __syncthreads();

    const int rsel = lane & 15;
    const int kgb = (lane >> 4) * 16; // byte offset: 8 contiguous k per lane-group
    bf16x8 fah[4], fal[4], fbh[4], fbl[4];
    #pragma unroll
    for (int q = 0; q < 4; ++q) {
      const int ar = wm * 64 + q * 16 + rsel;
      fah[q] = *(const bf16x8*)((const char*)sAh + ar * 64 + kgb);
      fal[q] = *(const bf16x8*)((const char*)sAl + ar * 64 + kgb);
      const int br = wn * 64 + q * 16 + rsel;
      fbh[q] = *(const bf16x8*)((const char*)sBh + br * 64 + kgb);
      fbl[q] = *(const bf16x8*)((const char*)sBl + br * 64 + kgb);
    }
    #pragma unroll
    for (int mi = 0; mi < 4; ++mi) {
      #pragma unroll
      for (int ni = 0; ni < 4; ++ni) {
        acc[mi][ni] = __builtin_amdgcn_mfma_f32_16x16x32_bf16(fah[mi], fbh[ni], acc[mi][ni], 0, 0, 0);
        acc[mi][ni] = __builtin_amdgcn_mfma_f32_16x16x32_bf16(fah[mi], fbl[ni], acc[mi][ni], 0, 0, 0);
        acc[mi][ni] = __builtin_amdgcn_mfma_f32_16x16x32_bf16(fal[mi], fbh[ni], acc[mi][ni], 0, 0, 0);
      }
    }
    __syncthreads();
  }

  // epilogue: C/D layout col=lane&15, row=(lane>>4)*4+reg
  const int col = lane & 15;
  const int rg = (lane >> 4) * 4;
  #pragma unroll
  for (int mi = 0; mi < 4; ++mi) {
    #pragma unroll
    for (int ni = 0; ni < 4; ++ni) {
      const size_t m = bm0 + (size_t)(wm * 64 + mi * 16 + rg);
      const size_t n = bn0 + (size_t)(wn * 64 + ni * 16 + col);
      float* cp = C + m * 4096 + n;
      #pragma unroll
      for (int rr = 0; rr < 4; ++rr) cp[(size_t)rr * 4096] = acc[mi][ni][rr];
    }
  }
}

extern "C" void kernel_launch(void* const* d_in, const int* in_sizes, int n_in,
                              void* d_out, int out_size, void* d_ws, size_t ws_size,
                              hipStream_t stream) {
  const float* x = (const float*)d_in[0];
  const float* b0 = (const float*)d_in[1];
  const float* b1 = (const float*)d_in[2];
  const float* b2 = (const float*)d_in[3];
  const float* b3 = (const float*)d_in[4];
  const float* b4 = (const float*)d_in[5];
  float* out = (float*)d_out;

  // workspace layout: Ah | Al | Bh | Bl, each 4096*4416 bf16 (36.2 MB) -> 145 MB total
  const size_t SA = (size_t)4096 * KPAD;
  unsigned short* Ah = (unsigned short*)d_ws;
  unsigned short* Al = Ah + SA;
  unsigned short* Bh = Al + SA;
  unsigned short* Bl = Bh + SA;

  dwt_kernel<<<4096, 256, 0, stream>>>(x, Ah, Al);
  bconv_kernel<<<dim3(KPAD / 64, 4096 / 64), 256, 0, stream>>>(b0, b1, b2, b3, b4, Bh, Bl);
  gemm_kernel<<<1024, 256, 0, stream>>>(Ah, Al, Bh, Bl, out);
}

// Round 3
// 628.258 us; speedup vs baseline: 1.3724x; 1.3724x over previous
//
#include <hip/hip_runtime.h>
#include <stdint.h>

// WaveletKAN: out = sum_s wavedec(x)[s] @ basis_s[:K_s]
// K segments (db4, symmetric, 4 levels from N=4096): cA4=262, cD4=262, cD3=518, cD2=1029, cD1=2051
// ONE GEMM [4096 x 4416] @ [4416 x 4096], segments padded to x64 (zeros).
// bf16x3 split precision: acc = AhBh + AhBl + AlBh.
// GEMM structure: 256x256 tile, BK=32, 8 waves (2Mx4N), 4-phase interleave per K-tile,
// double-buffered LDS (128 KiB), st_16x32 XOR swizzle (write-side pre-swizzled global src),
// counted staging (issue phases 0-1, single vmcnt(0) at phase 3), setprio around MFMA.

#define KPAD 4416

typedef __bf16 bf16x8 __attribute__((ext_vector_type(8)));
typedef float f32x4 __attribute__((ext_vector_type(4)));

__device__ __forceinline__ void split_bf(float v, unsigned short& h, unsigned short& l) {
  uint32_t u = __builtin_bit_cast(uint32_t, v);
  uint32_t hr = (u + 0x7FFFu + ((u >> 16) & 1u)) >> 16;
  h = (unsigned short)hr;
  float hf = __builtin_bit_cast(float, hr << 16);
  float d = v - hf;
  uint32_t du = __builtin_bit_cast(uint32_t, d);
  uint32_t lr = (du + 0x7FFFu + ((du >> 16) & 1u)) >> 16;
  l = (unsigned short)lr;
}

// ---------------- DWT: 4 levels of db4 'symmetric' per row, writes split coeffs ----------------
__global__ __launch_bounds__(256) void dwt_kernel(const float* __restrict__ x,
                                                  unsigned short* __restrict__ Ah,
                                                  unsigned short* __restrict__ Al) {
  __shared__ float bufA[4096];
  __shared__ float bufB[2052];
  const int tid = threadIdx.x;
  const int row = blockIdx.x;
  const size_t rowbase = (size_t)row * KPAD;

  {
    const float4* src = (const float4*)(x + (size_t)row * 4096);
    float4* dst = (float4*)bufA;
    for (int i = tid; i < 1024; i += 256) dst[i] = src[i];
  }
  __syncthreads();

  const float LOr[8] = {0.23037781330885523f, 0.7148465705525415f, 0.6308807679295904f,
                        -0.02798376941698385f, -0.18703481171888114f, 0.030841381835986965f,
                        0.032883011666982945f, -0.010597401784997278f};
  const float HIr[8] = {-0.010597401784997278f, -0.032883011666982945f, 0.030841381835986965f,
                        0.18703481171888114f, -0.02798376941698385f, -0.6308807679295904f,
                        0.7148465705525415f, -0.23037781330885523f};
  const int dOff[4] = {2304, 1216, 640, 320};

  float* cur = bufA;
  float* nxt = bufB;
  int N = 4096;
  for (int l = 0; l < 4; ++l) {
    const int M = (N + 7) >> 1;
    for (int t = tid; t < M; t += 256) {
      float lo = 0.f, hi = 0.f;
      const int base = 1 + 2 * t;
      #pragma unroll
      for (int j = 0; j < 8; ++j) {
        const int i = base + j;
        const int idx = (i < 7) ? (6 - i) : ((i < N + 7) ? (i - 7) : (2 * N + 6 - i));
        const float v = cur[idx];
        lo = fmaf(v, LOr[j], lo);
        hi = fmaf(v, HIr[j], hi);
      }
      unsigned short hh, hl;
      split_bf(hi, hh, hl);
      Ah[rowbase + dOff[l] + t] = hh;
      Al[rowbase + dOff[l] + t] = hl;
      if (l < 3) {
        nxt[t] = lo;
      } else {
        unsigned short ch, cl;
        split_bf(lo, ch, cl);
        Ah[rowbase + t] = ch;
        Al[rowbase + t] = cl;
      }
    }
    __syncthreads();
    float* tmp = cur; cur = nxt; nxt = tmp;
    N = M;
  }

  const int gs[5] = {262, 582, 1158, 2245, 4355};
  const int ge[5] = {320, 640, 1216, 2304, 4416};
  #pragma unroll
  for (int g = 0; g < 5; ++g)
    for (int i = gs[g] + tid; i < ge[g]; i += 256) {
      Ah[rowbase + i] = 0;
      Al[rowbase + i] = 0;
    }
}

// ---------------- Basis gather + transpose + bf16 hi/lo split: Bt[n][k] ----------------
__global__ __launch_bounds__(256) void bconv_kernel(const float* __restrict__ b0, const float* __restrict__ b1,
                                                    const float* __restrict__ b2, const float* __restrict__ b3,
                                                    const float* __restrict__ b4,
                                                    unsigned short* __restrict__ Bh,
                                                    unsigned short* __restrict__ Bl) {
  __shared__ float tile[64][65];
  const int tid = threadIdx.x;
  const int k0 = blockIdx.x * 64;
  const int n0 = blockIdx.y * 64;
  const int s = (k0 >= 2304) ? 4 : (k0 >= 1216) ? 3 : (k0 >= 640) ? 2 : (k0 >= 320) ? 1 : 0;
  const int offs[5] = {0, 320, 640, 1216, 2304};
  const int lens[5] = {262, 262, 518, 1029, 2051};
  const float* srcs[5] = {b0, b1, b2, b3, b4};
  const float* src = srcs[s];
  const int kl0 = k0 - offs[s];
  const int len = lens[s];

  #pragma unroll
  for (int r = 0; r < 4; ++r) {
    const int kr = r * 16 + (tid >> 4);
    const int nc = (tid & 15) * 4;
    const int kl = kl0 + kr;
    float4 v = make_float4(0.f, 0.f, 0.f, 0.f);
    if (kl < len) v = *(const float4*)(src + (size_t)kl * 4096 + n0 + nc);
    tile[kr][nc] = v.x; tile[kr][nc + 1] = v.y; tile[kr][nc + 2] = v.z; tile[kr][nc + 3] = v.w;
  }
  __syncthreads();

  const int nl = tid >> 2;
  const int kg = (tid & 3) * 16;
  uint4 hv[2]; uint4 lv[2];
  unsigned short* hb = (unsigned short*)hv;
  unsigned short* lb = (unsigned short*)lv;
  #pragma unroll
  for (int j = 0; j < 16; ++j) {
    unsigned short h, l;
    split_bf(tile[kg + j][nl], h, l);
    hb[j] = h; lb[j] = l;
  }
  const size_t dst = (size_t)(n0 + nl) * KPAD + (size_t)(k0 + kg);
  ((uint4*)(Bh + dst))[0] = hv[0];
  ((uint4*)(Bh + dst))[1] = hv[1];
  ((uint4*)(Bl + dst))[0] = lv[0];
  ((uint4*)(Bl + dst))[1] = lv[1];
}

// ---------------- GEMM: 256x256 tile, BK=32, 8 waves, 4-phase, dbuf + swizzle ----------------
#define GLD16(g, l)                                                                              \
  __builtin_amdgcn_global_load_lds((const __attribute__((address_space(1))) void*)(g),           \
                                   (__attribute__((address_space(3))) void*)(l), 16, 0, 0)

#define MFMA(a, b, c) __builtin_amdgcn_mfma_f32_16x16x32_bf16((a), (b), (c), 0, 0, 0)

__global__ __launch_bounds__(512, 2) void gemm_kernel(const unsigned short* __restrict__ Ah,
                                                      const unsigned short* __restrict__ Al,
                                                      const unsigned short* __restrict__ Bh,
                                                      const unsigned short* __restrict__ Bl,
                                                      float* __restrict__ C) {
  // LDS: buf{0,1} x {Ah,Al,Bh,Bl} x [256 rows][64B] ; 2*4*16KB = 128 KiB
  __shared__ __align__(16) char smem[131072];
  const int tid = threadIdx.x;
  const int wave = tid >> 6;
  const int lane = tid & 63;

  // XCD-aware bijective swizzle (256 blocks % 8 == 0, 32 per XCD)
  const int bid = blockIdx.x;
  const int wg = (bid & 7) * 32 + (bid >> 3);
  const int tm = wg >> 4, tn = wg & 15;
  const size_t bm0 = (size_t)tm * 256;
  const size_t bn0 = (size_t)tn * 256;
  const int wm = wave >> 2, wn = wave & 3; // 2x4 wave grid, 128x64 per wave

  // ---- staging addressing: LDS linear [row][4 chunks of 16B]; global source chunk
  // pre-swizzled (st_16x32: flip chunk bit1 when row bit3 set) so swizzled READS see G[a].
  const int srow = tid >> 2;                       // 0..127 (r adds 128)
  const int scs = (tid & 3) ^ (((srow >> 3) & 1) << 1);
  const size_t aoff = (bm0 + (size_t)srow) * KPAD + (size_t)scs * 8;
  const size_t boff = (bn0 + (size_t)srow) * KPAD + (size_t)scs * 8;
  const int wbase = wave * 1024;                   // wave-uniform LDS byte base

#define STAGE_A(nb, kk)                                                   \
  do {                                                                    \
    char* lb = smem + (nb) * 65536 + wbase;                               \
    GLD16(Ah + aoff + (kk), lb);                                          \
    GLD16(Ah + aoff + 128 * KPAD + (kk), lb + 8192);                      \
    GLD16(Al + aoff + (kk), lb + 16384);                                  \
    GLD16(Al + aoff + 128 * KPAD + (kk), lb + 16384 + 8192);              \
  } while (0)
#define STAGE_B(nb, kk)                                                   \
  do {                                                                    \
    char* lb = smem + (nb) * 65536 + wbase;                               \
    GLD16(Bh + boff + (kk), lb + 32768);                                  \
    GLD16(Bh + boff + 128 * KPAD + (kk), lb + 32768 + 8192);              \
    GLD16(Bl + boff + (kk), lb + 49152);                                  \
    GLD16(Bl + boff + 128 * KPAD + (kk), lb + 49152 + 8192);              \
  } while (0)

  // ---- fragment read addressing (swizzled): row*64 + (kchunk*16 ^ ((row>>3&1)<<5))
  const int rsel = lane & 15;
  const int kswz = ((lane >> 4) * 16) ^ (((rsel >> 3) & 1) << 5);
  const int arb = (wm * 128 + rsel) * 64 + kswz; // + mi*1024
  const int brb = (wn * 64 + rsel) * 64 + kswz;  // + q*1024

  f32x4 acc[8][4] = {};

  // ---- prologue: stage tile 0 into buf0
  STAGE_A(0, 0);
  STAGE_B(0, 0);
  asm volatile("s_waitcnt vmcnt(0)" ::: "memory");
  __builtin_amdgcn_s_barrier();

  const int NKT = KPAD / 32; // 138
  for (int t = 0; t < NKT; ++t) {
    char* cb = smem + (t & 1) * 65536;
    const int nb = (t & 1) ^ 1;
    const bool st = (t + 1 < NKT);
    const size_t kn = (size_t)(t + 1) * 32;

    bf16x8 fbh[4], fbl[4];

    #pragma unroll
    for (int p = 0; p < 4; ++p) {
      // ds-load register subtiles for this phase
      if (p == 0) {
        #pragma unroll
        for (int q = 0; q < 4; ++q) {
          fbh[q] = *(const bf16x8*)(cb + 32768 + brb + q * 1024);
          fbl[q] = *(const bf16x8*)(cb + 49152 + brb + q * 1024);
        }
      }
      bf16x8 fah0 = *(const bf16x8*)(cb + arb + (2 * p) * 1024);
      bf16x8 fal0 = *(const bf16x8*)(cb + 16384 + arb + (2 * p) * 1024);
      bf16x8 fah1 = *(const bf16x8*)(cb + arb + (2 * p + 1) * 1024);
      bf16x8 fal1 = *(const bf16x8*)(cb + 16384 + arb + (2 * p + 1) * 1024);

      // issue next-tile staging early (phases 0-1) so the phase-3 drain is covered
      if (p == 0 && st) STAGE_A(nb, kn);
      if (p == 1 && st) STAGE_B(nb, kn);

      __builtin_amdgcn_s_barrier();
      __builtin_amdgcn_s_setprio(1);
      #pragma unroll
      for (int ni = 0; ni < 4; ++ni) {
        acc[2 * p][ni] = MFMA(fah0, fbh[ni], acc[2 * p][ni]);
        acc[2 * p][ni] = MFMA(fah0, fbl[ni], acc[2 * p][ni]);
        acc[2 * p][ni] = MFMA(fal0, fbh[ni], acc[2 * p][ni]);
        acc[2 * p + 1][ni] = MFMA(fah1, fbh[ni], acc[2 * p + 1][ni]);
        acc[2 * p + 1][ni] = MFMA(fah1, fbl[ni], acc[2 * p + 1][ni]);
        acc[2 * p + 1][ni] = MFMA(fal1, fbh[ni], acc[2 * p + 1][ni]);
      }
      __builtin_amdgcn_s_setprio(0);
      if (p == 3) asm volatile("s_waitcnt vmcnt(0)" ::: "memory"); // next tile staged; fences reorder
      __builtin_amdgcn_s_barrier();
    }
  }

  // ---- epilogue: C/D layout col=lane&15, row=(lane>>4)*4+reg
  const int col = lane & 15;
  const int rg = (lane >> 4) * 4;
  #pragma unroll
  for (int mi = 0; mi < 8; ++mi) {
    #pragma unroll
    for (int ni = 0; ni < 4; ++ni) {
      const size_t m = bm0 + (size_t)(wm * 128 + mi * 16 + rg);
      const size_t n = bn0 + (size_t)(wn * 64 + ni * 16 + col);
      float* cp = C + m * 4096 + n;
      #pragma unroll
      for (int rr = 0; rr < 4; ++rr) cp[(size_t)rr * 4096] = acc[mi][ni][rr];
    }
  }
}

extern "C" void kernel_launch(void* const* d_in, const int* in_sizes, int n_in,
                              void* d_out, int out_size, void* d_ws, size_t ws_size,
                              hipStream_t stream) {
  const float* x = (const float*)d_in[0];
  const float* b0 = (const float*)d_in[1];
  const float* b1 = (const float*)d_in[2];
  const float* b2 = (const float*)d_in[3];
  const float* b3 = (const float*)d_in[4];
  const float* b4 = (const float*)d_in[5];
  float* out = (float*)d_out;

  const size_t SA = (size_t)4096 * KPAD;
  unsigned short* Ah = (unsigned short*)d_ws;
  unsigned short* Al = Ah + SA;
  unsigned short* Bh = Al + SA;
  unsigned short* Bl = Bh + SA;

  dwt_kernel<<<4096, 256, 0, stream>>>(x, Ah, Al);
  bconv_kernel<<<dim3(KPAD / 64, 4096 / 64), 256, 0, stream>>>(b0, b1, b2, b3, b4, Bh, Bl);
  gemm_kernel<<<256, 512, 0, stream>>>(Ah, Al, Bh, Bl, out);
}